// Round 1
// baseline (300.768 us; speedup 1.0000x reference)
//
#include <hip/hip_runtime.h>
#include <math.h>

typedef _Float16 half_t;
typedef _Float16 halfx8 __attribute__((ext_vector_type(8)));
typedef _Float16 halfx4 __attribute__((ext_vector_type(4)));
typedef float floatx4 __attribute__((ext_vector_type(4)));

typedef __attribute__((address_space(3))) void lds_t;
typedef const __attribute__((address_space(1))) void gmem_t;

static constexpr int kB = 2;
static constexpr int kLD = 2048;
static constexpr int kLM = 2048;
static constexpr int kD = 1024;
static constexpr int kH = 16;
static constexpr int kDH = 64;

// ---------------------------------------------------------------------------
// 1) f32 -> f16 conversion of the 5 operands (X_dec, X_enc, Wq, Wk, Wv)
// ---------------------------------------------------------------------------
__global__ __launch_bounds__(256) void convert_all(
    const float* __restrict__ s0, const float* __restrict__ s1,
    const float* __restrict__ s2, const float* __restrict__ s3,
    const float* __restrict__ s4,
    half_t* __restrict__ d0, half_t* __restrict__ d1,
    half_t* __restrict__ d2, half_t* __restrict__ d3, half_t* __restrict__ d4)
{
  const size_t N0 = (size_t)kB * kLD * kD;       // 4,194,304
  const size_t N1 = N0 + (size_t)kB * kLM * kD;  // 8,388,608
  const size_t N2 = N1 + (size_t)kD * kD;        // 9,437,184
  const size_t N3 = N2 + (size_t)kD * kD;        // 10,485,760
  const size_t N4 = N3 + (size_t)kD * kD;        // 11,534,336
  size_t idx = ((size_t)blockIdx.x * blockDim.x + threadIdx.x) * 4;
  if (idx >= N4) return;
  const float* s; half_t* d; size_t off;
  if (idx < N0)      { s = s0; d = d0; off = idx; }
  else if (idx < N1) { s = s1; d = d1; off = idx - N0; }
  else if (idx < N2) { s = s2; d = d2; off = idx - N1; }
  else if (idx < N3) { s = s3; d = d3; off = idx - N2; }
  else               { s = s4; d = d4; off = idx - N3; }
  float4 v = *(const float4*)(s + off);
  halfx4 hv;
  hv[0] = (half_t)v.x; hv[1] = (half_t)v.y; hv[2] = (half_t)v.z; hv[3] = (half_t)v.w;
  *(halfx4*)(d + off) = hv;
}

// ---------------------------------------------------------------------------
// 2) Fused QKV projection GEMM: C[4096,1024] = X[4096,1024] @ W^T + b
//    mode 0: Q (x0.125, layout [B,H,LD,DH]); mode 1: K ([B,H,LM,DH]);
//    mode 2: V transposed ([B,H,DH,LM]).
//    m97 structure: 128x128 tile, BK=64, global_load_lds w=16, linear LDS.
// ---------------------------------------------------------------------------
__global__ __launch_bounds__(256, 2) void qkv_gemm(
    const half_t* __restrict__ xdec, const half_t* __restrict__ xenc,
    const half_t* __restrict__ wq, const half_t* __restrict__ wk,
    const half_t* __restrict__ wv,
    const float* __restrict__ bq, const float* __restrict__ bk,
    const float* __restrict__ bv,
    half_t* __restrict__ qbuf, half_t* __restrict__ kbuf,
    half_t* __restrict__ vtbuf)
{
  const int mode = blockIdx.z;
  const half_t* Ag = (mode == 0) ? xdec : xenc;
  const half_t* Bg = (mode == 0) ? wq : (mode == 1) ? wk : wv;
  const float* bias = (mode == 0) ? bq : (mode == 1) ? bk : bv;

  __shared__ alignas(16) half_t Alds[128 * 64];
  __shared__ alignas(16) half_t Blds[128 * 64];

  const int m0 = blockIdx.x * 128;
  const int n0 = blockIdx.y * 128;
  const int tid = threadIdx.x;
  const int lane = tid & 63;
  const int wid = tid >> 6;
  const int wr = wid >> 1, wc = wid & 1;
  const int l15 = lane & 15, lhi = lane >> 4;

  floatx4 acc[4][4] = {};

  for (int k0 = 0; k0 < kD; k0 += 64) {
    __syncthreads();  // previous tile's ds_reads done before overwrite
#pragma unroll
    for (int i = 0; i < 4; ++i) {
      const int ob = wid * 4096 + i * 1024;  // wave-uniform LDS byte base
      const int lo = ob + lane * 16;         // per-lane linear byte offset
      const int row = lo >> 7;
      const int colh = (lo & 127) >> 1;      // half-element column
      const half_t* ga = Ag + (size_t)(m0 + row) * kD + k0 + colh;
      const half_t* gb = Bg + (size_t)(n0 + row) * kD + k0 + colh;
      __builtin_amdgcn_global_load_lds((gmem_t*)ga, (lds_t*)((char*)Alds + ob), 16, 0, 0);
      __builtin_amdgcn_global_load_lds((gmem_t*)gb, (lds_t*)((char*)Blds + ob), 16, 0, 0);
    }
    __syncthreads();  // drains vmcnt

#pragma unroll
    for (int ks = 0; ks < 2; ++ks) {
      halfx8 af[4], bf[4];
#pragma unroll
      for (int mt = 0; mt < 4; ++mt)
        af[mt] = *(const halfx8*)(Alds + (wr * 64 + mt * 16 + l15) * 64 + ks * 32 + lhi * 8);
#pragma unroll
      for (int nt = 0; nt < 4; ++nt)
        bf[nt] = *(const halfx8*)(Blds + (wc * 64 + nt * 16 + l15) * 64 + ks * 32 + lhi * 8);
#pragma unroll
      for (int mt = 0; mt < 4; ++mt)
#pragma unroll
        for (int nt = 0; nt < 4; ++nt)
          acc[mt][nt] = __builtin_amdgcn_mfma_f32_16x16x32_f16(af[mt], bf[nt], acc[mt][nt], 0, 0, 0);
    }
  }

  // Epilogue: bias (+0.125 scale for Q), store f16 in attention-friendly layouts.
#pragma unroll
  for (int nt = 0; nt < 4; ++nt) {
    const int n = n0 + wc * 64 + nt * 16 + l15;
    const float bb = bias[n];
    const int h = n >> 6, dv = n & 63;
#pragma unroll
    for (int mt = 0; mt < 4; ++mt) {
#pragma unroll
      for (int r = 0; r < 4; ++r) {
        const int m = m0 + wr * 64 + mt * 16 + lhi * 4 + r;
        const int b = m >> 11, rowl = m & 2047;
        float v = acc[mt][nt][r] + bb;
        if (mode == 0) {
          v *= 0.125f;  // 1/sqrt(DH), exact in fp
          qbuf[((size_t)(b * kH + h) * kLD + rowl) * kDH + dv] = (half_t)v;
        } else if (mode == 1) {
          kbuf[((size_t)(b * kH + h) * kLM + rowl) * kDH + dv] = (half_t)v;
        } else {
          vtbuf[((size_t)(b * kH + h) * kDH + dv) * kLM + rowl] = (half_t)v;
        }
      }
    }
  }
}

// ---------------------------------------------------------------------------
// 3) Flash-style masked cross-attention.
//    Block = (b, h, 64 q-rows); 4 waves x 16 q-rows; KV tiles of 64 in padded
//    LDS (pitch 72 halves = 144B -> 2-way conflicts only). Online softmax.
// ---------------------------------------------------------------------------
__global__ __launch_bounds__(256, 2) void attn_kernel(
    const half_t* __restrict__ qbuf, const half_t* __restrict__ kbuf,
    const half_t* __restrict__ vtbuf, const int* __restrict__ amask,
    const int* __restrict__ hmask, float* __restrict__ out)
{
  // XCD swizzle: all 32 q-tiles of a head land on one XCD (id % 8 round-robin)
  const int d = blockIdx.x;                 // 0..1023
  const int bh = (d & 7) + ((d >> 8) << 3); // 0..31
  const int qt = (d >> 3) & 31;
  const int b = bh >> 4, h = bh & 15;

  const int tid = threadIdx.x;
  const int lane = tid & 63;
  const int wid = tid >> 6;
  const int l15 = lane & 15, lhi = lane >> 4;

  __shared__ alignas(16) half_t Klds[64 * 72];
  __shared__ alignas(16) half_t Vlds[64 * 72];       // V^T tile: [dv][kv]
  __shared__ alignas(16) half_t Plds[4 * 16 * 72];   // per-wave P relayout
  __shared__ float maskadd[kLM];

  for (int i = tid; i < kLM; i += 256)
    maskadd[i] = amask[b * kLM + i] ? 0.0f : -1e30f;

  const int q0 = qt * 64 + wid * 16;
  const half_t* kbase = kbuf + (size_t)bh * kLM * kDH;
  const half_t* vtbase = vtbuf + (size_t)bh * kDH * kLM;
  half_t* pbase = Plds + wid * (16 * 72);

  // Q fragments held in registers for the whole block (rows q0..q0+15)
  halfx8 qf[2];
#pragma unroll
  for (int ks = 0; ks < 2; ++ks)
    qf[ks] = *(const halfx8*)(qbuf + ((size_t)bh * kLD + q0 + l15) * kDH + ks * 32 + lhi * 8);

  floatx4 ctx[4] = {};
  float m_run[4], l_run[4];
#pragma unroll
  for (int r = 0; r < 4; ++r) { m_run[r] = -1e30f; l_run[r] = 0.0f; }

  for (int kv0 = 0; kv0 < kLM; kv0 += 64) {
    // stage K tile [kv][d] and V^T tile [dv][kv] (reg-staged, padded LDS)
    int4 kreg[2], vreg[2];
#pragma unroll
    for (int i = 0; i < 2; ++i) {
      const int c = tid + 256 * i;
      const int row = c >> 3, col8 = c & 7;
      kreg[i] = *(const int4*)(kbase + (size_t)(kv0 + row) * kDH + col8 * 8);
      vreg[i] = *(const int4*)(vtbase + (size_t)row * kLM + kv0 + col8 * 8);
    }
    __syncthreads();  // previous tile's compute done
#pragma unroll
    for (int i = 0; i < 2; ++i) {
      const int c = tid + 256 * i;
      const int row = c >> 3, col8 = c & 7;
      *(int4*)((char*)Klds + row * 144 + col8 * 16) = kreg[i];
      *(int4*)((char*)Vlds + row * 144 + col8 * 16) = vreg[i];
    }
    __syncthreads();

    // S = (Q*0.125) K^T   (C layout: row q = lhi*4+r, col kv = l15)
    floatx4 s[4] = {};
#pragma unroll
    for (int t = 0; t < 4; ++t)
#pragma unroll
      for (int ks = 0; ks < 2; ++ks) {
        halfx8 kf = *(const halfx8*)(Klds + (t * 16 + l15) * 72 + ks * 32 + lhi * 8);
        s[t] = __builtin_amdgcn_mfma_f32_16x16x32_f16(qf[ks], kf, s[t], 0, 0, 0);
      }

    // additive mask
    float mk[4];
#pragma unroll
    for (int t = 0; t < 4; ++t) mk[t] = maskadd[kv0 + t * 16 + l15];
#pragma unroll
    for (int t = 0; t < 4; ++t)
#pragma unroll
      for (int r = 0; r < 4; ++r) s[t][r] += mk[t];

    // row max across the 16-lane group
    float mx[4];
#pragma unroll
    for (int r = 0; r < 4; ++r)
      mx[r] = fmaxf(fmaxf(s[0][r], s[1][r]), fmaxf(s[2][r], s[3][r]));
#pragma unroll
    for (int dlt = 1; dlt < 16; dlt <<= 1)
#pragma unroll
      for (int r = 0; r < 4; ++r)
        mx[r] = fmaxf(mx[r], __shfl_xor(mx[r], dlt));

    float sc[4], ssum[4];
#pragma unroll
    for (int r = 0; r < 4; ++r) {
      const float mn = fmaxf(m_run[r], mx[r]);
      sc[r] = __expf(m_run[r] - mn);
      m_run[r] = mn;
      ssum[r] = 0.0f;
    }
    // P = exp(S - m); write to per-wave LDS for A-fragment relayout
#pragma unroll
    for (int t = 0; t < 4; ++t)
#pragma unroll
      for (int r = 0; r < 4; ++r) {
        const float p = __expf(s[t][r] - m_run[r]);
        ssum[r] += p;
        pbase[(lhi * 4 + r) * 72 + t * 16 + l15] = (half_t)p;
      }
#pragma unroll
    for (int dlt = 1; dlt < 16; dlt <<= 1)
#pragma unroll
      for (int r = 0; r < 4; ++r)
        ssum[r] += __shfl_xor(ssum[r], dlt);
#pragma unroll
    for (int r = 0; r < 4; ++r) l_run[r] = l_run[r] * sc[r] + ssum[r];
#pragma unroll
    for (int t = 0; t < 4; ++t)
#pragma unroll
      for (int r = 0; r < 4; ++r) ctx[t][r] *= sc[r];

    // ctx += P @ V   (A = P from Plds; B = V^T rows = dv)
    halfx8 pf[2];
#pragma unroll
    for (int ks = 0; ks < 2; ++ks)
      pf[ks] = *(const halfx8*)(pbase + l15 * 72 + ks * 32 + lhi * 8);
#pragma unroll
    for (int t = 0; t < 4; ++t)
#pragma unroll
      for (int ks = 0; ks < 2; ++ks) {
        halfx8 vf = *(const halfx8*)(Vlds + (t * 16 + l15) * 72 + ks * 32 + lhi * 8);
        ctx[t] = __builtin_amdgcn_mfma_f32_16x16x32_f16(pf[ks], vf, ctx[t], 0, 0, 0);
      }
  }

  // epilogue: normalize, apply head_mask, store f32 [B, LD, H*DH]
  float inv[4];
#pragma unroll
  for (int r = 0; r < 4; ++r) {
    const int q = q0 + lhi * 4 + r;
    const float hm = 1.0f - (float)hmask[b * kLD + q];
    inv[r] = hm / l_run[r];
  }
#pragma unroll
  for (int t = 0; t < 4; ++t) {
    const int dv = t * 16 + l15;
#pragma unroll
    for (int r = 0; r < 4; ++r) {
      const int q = q0 + lhi * 4 + r;
      out[((size_t)(b * kLD + q) << 10) + (h << 6) + dv] = ctx[t][r] * inv[r];
    }
  }
}

// ---------------------------------------------------------------------------
extern "C" void kernel_launch(void* const* d_in, const int* in_sizes, int n_in,
                              void* d_out, int out_size, void* d_ws, size_t ws_size,
                              hipStream_t stream)
{
  const float* hs   = (const float*)d_in[0];
  const float* ehs  = (const float*)d_in[1];
  const int*   am   = (const int*)d_in[2];
  const int*   hm   = (const int*)d_in[3];
  const float* Wq   = (const float*)d_in[4];
  const float* bq   = (const float*)d_in[5];
  const float* Wk   = (const float*)d_in[6];
  const float* bk   = (const float*)d_in[7];
  const float* Wv   = (const float*)d_in[8];
  const float* bv   = (const float*)d_in[9];
  float* out = (float*)d_out;

  char* ws = (char*)d_ws;
  half_t* xdec_h = (half_t*)(ws);
  half_t* xenc_h = (half_t*)(ws + (8ull << 20));
  half_t* wq_h   = (half_t*)(ws + (16ull << 20));
  half_t* wk_h   = (half_t*)(ws + (18ull << 20));
  half_t* wv_h   = (half_t*)(ws + (20ull << 20));
  half_t* q_buf  = (half_t*)(ws + (22ull << 20));
  half_t* k_buf  = (half_t*)(ws + (30ull << 20));
  half_t* vt_buf = (half_t*)(ws + (38ull << 20));

  convert_all<<<11264, 256, 0, stream>>>(hs, ehs, Wq, Wk, Wv,
                                         xdec_h, xenc_h, wq_h, wk_h, wv_h);
  qkv_gemm<<<dim3(32, 8, 3), 256, 0, stream>>>(xdec_h, xenc_h, wq_h, wk_h, wv_h,
                                               bq, bk, bv, q_buf, k_buf, vt_buf);
  attn_kernel<<<1024, 256, 0, stream>>>(q_buf, k_buf, vt_buf, am, hm, out);
}

// Round 3
// 268.107 us; speedup vs baseline: 1.1218x; 1.1218x over previous
//
#include <hip/hip_runtime.h>
#include <math.h>

typedef _Float16 half_t;
typedef _Float16 halfx8 __attribute__((ext_vector_type(8)));
typedef _Float16 halfx4 __attribute__((ext_vector_type(4)));
typedef _Float16 halfx2 __attribute__((ext_vector_type(2)));
typedef float floatx4 __attribute__((ext_vector_type(4)));
typedef float floatx16 __attribute__((ext_vector_type(16)));
typedef unsigned int uintx2 __attribute__((ext_vector_type(2)));
typedef unsigned int uintx4 __attribute__((ext_vector_type(4)));

typedef __attribute__((address_space(3))) void lds_t;
typedef const __attribute__((address_space(1))) void gmem_t;

static constexpr int kB = 2;
static constexpr int kLD = 2048;
static constexpr int kLM = 2048;
static constexpr int kD = 1024;
static constexpr int kH = 16;
static constexpr int kDH = 64;

__device__ __forceinline__ float exp2_fast(float x) {
#if __has_builtin(__builtin_amdgcn_exp2f)
  return __builtin_amdgcn_exp2f(x);
#else
  return exp2f(x);
#endif
}

// ---------------------------------------------------------------------------
// 1) f32 -> f16 conversion of the 5 operands (X_dec, X_enc, Wq, Wk, Wv)
// ---------------------------------------------------------------------------
__global__ __launch_bounds__(256) void convert_all(
    const float* __restrict__ s0, const float* __restrict__ s1,
    const float* __restrict__ s2, const float* __restrict__ s3,
    const float* __restrict__ s4,
    half_t* __restrict__ d0, half_t* __restrict__ d1,
    half_t* __restrict__ d2, half_t* __restrict__ d3, half_t* __restrict__ d4)
{
  const size_t N0 = (size_t)kB * kLD * kD;
  const size_t N1 = N0 + (size_t)kB * kLM * kD;
  const size_t N2 = N1 + (size_t)kD * kD;
  const size_t N3 = N2 + (size_t)kD * kD;
  const size_t N4 = N3 + (size_t)kD * kD;
  size_t idx = ((size_t)blockIdx.x * blockDim.x + threadIdx.x) * 4;
  if (idx >= N4) return;
  const float* s; half_t* d; size_t off;
  if (idx < N0)      { s = s0; d = d0; off = idx; }
  else if (idx < N1) { s = s1; d = d1; off = idx - N0; }
  else if (idx < N2) { s = s2; d = d2; off = idx - N1; }
  else if (idx < N3) { s = s3; d = d3; off = idx - N2; }
  else               { s = s4; d = d4; off = idx - N3; }
  float4 v = *(const float4*)(s + off);
  halfx4 hv;
  hv[0] = (half_t)v.x; hv[1] = (half_t)v.y; hv[2] = (half_t)v.z; hv[3] = (half_t)v.w;
  *(halfx4*)(d + off) = hv;
}

// ---------------------------------------------------------------------------
// 2) Fused QKV projection GEMM (m97 structure). Q scaled by 0.125*log2(e) so
//    attention softmax can run entirely in exp2 domain.
// ---------------------------------------------------------------------------
__global__ __launch_bounds__(256, 2) void qkv_gemm(
    const half_t* __restrict__ xdec, const half_t* __restrict__ xenc,
    const half_t* __restrict__ wq, const half_t* __restrict__ wk,
    const half_t* __restrict__ wv,
    const float* __restrict__ bq, const float* __restrict__ bk,
    const float* __restrict__ bv,
    half_t* __restrict__ qbuf, half_t* __restrict__ kbuf,
    half_t* __restrict__ vtbuf)
{
  const int mode = blockIdx.z;
  const half_t* Ag = (mode == 0) ? xdec : xenc;
  const half_t* Bg = (mode == 0) ? wq : (mode == 1) ? wk : wv;
  const float* bias = (mode == 0) ? bq : (mode == 1) ? bk : bv;

  __shared__ alignas(16) half_t Alds[128 * 64];
  __shared__ alignas(16) half_t Blds[128 * 64];

  const int m0 = blockIdx.x * 128;
  const int n0 = blockIdx.y * 128;
  const int tid = threadIdx.x;
  const int lane = tid & 63;
  const int wid = tid >> 6;
  const int wr = wid >> 1, wc = wid & 1;
  const int l15 = lane & 15, lhi = lane >> 4;

  floatx4 acc[4][4] = {};

  for (int k0 = 0; k0 < kD; k0 += 64) {
    __syncthreads();
#pragma unroll
    for (int i = 0; i < 4; ++i) {
      const int ob = wid * 4096 + i * 1024;
      const int lo = ob + lane * 16;
      const int row = lo >> 7;
      const int colh = (lo & 127) >> 1;
      const half_t* ga = Ag + (size_t)(m0 + row) * kD + k0 + colh;
      const half_t* gb = Bg + (size_t)(n0 + row) * kD + k0 + colh;
      __builtin_amdgcn_global_load_lds((gmem_t*)ga, (lds_t*)((char*)Alds + ob), 16, 0, 0);
      __builtin_amdgcn_global_load_lds((gmem_t*)gb, (lds_t*)((char*)Blds + ob), 16, 0, 0);
    }
    __syncthreads();

#pragma unroll
    for (int ks = 0; ks < 2; ++ks) {
      halfx8 af[4], bf[4];
#pragma unroll
      for (int mt = 0; mt < 4; ++mt)
        af[mt] = *(const halfx8*)(Alds + (wr * 64 + mt * 16 + l15) * 64 + ks * 32 + lhi * 8);
#pragma unroll
      for (int nt = 0; nt < 4; ++nt)
        bf[nt] = *(const halfx8*)(Blds + (wc * 64 + nt * 16 + l15) * 64 + ks * 32 + lhi * 8);
#pragma unroll
      for (int mt = 0; mt < 4; ++mt)
#pragma unroll
        for (int nt = 0; nt < 4; ++nt)
          acc[mt][nt] = __builtin_amdgcn_mfma_f32_16x16x32_f16(af[mt], bf[nt], acc[mt][nt], 0, 0, 0);
    }
  }

#pragma unroll
  for (int nt = 0; nt < 4; ++nt) {
    const int n = n0 + wc * 64 + nt * 16 + l15;
    const float bb = bias[n];
    const int h = n >> 6, dv = n & 63;
#pragma unroll
    for (int mt = 0; mt < 4; ++mt) {
#pragma unroll
      for (int r = 0; r < 4; ++r) {
        const int m = m0 + wr * 64 + mt * 16 + lhi * 4 + r;
        const int b = m >> 11, rowl = m & 2047;
        float v = acc[mt][nt][r] + bb;
        if (mode == 0) {
          v *= 0.18033688011112042f;  // (1/sqrt(64)) * log2(e) -> exp2-domain scores
          qbuf[((size_t)(b * kH + h) * kLD + rowl) * kDH + dv] = (half_t)v;
        } else if (mode == 1) {
          kbuf[((size_t)(b * kH + h) * kLM + rowl) * kDH + dv] = (half_t)v;
        } else {
          vtbuf[((size_t)(b * kH + h) * kDH + dv) * kLM + rowl] = (half_t)v;
        }
      }
    }
  }
}

// ---------------------------------------------------------------------------
// 3) Flash attention, swapped-QK^T 32x32 structure (m214 port).
//    Block = (b,h, 128 q-rows), 4 waves x 32 q-rows. KV tile = 64.
//    Lane owns one q column: softmax is in-register; P->PV via
//    cvt_pkrtz + permlane32_swap (no LDS round-trip).
// ---------------------------------------------------------------------------
__global__ __launch_bounds__(256, 2) void attn_kernel(
    const half_t* __restrict__ qbuf, const half_t* __restrict__ kbuf,
    const half_t* __restrict__ vtbuf, const int* __restrict__ amask,
    const int* __restrict__ hmask, float* __restrict__ out)
{
  // XCD swizzle: 64 consecutive blocks (4 bh x 16 q-tiles) per XCD
  const int x = blockIdx.x;
  const int gid = (x & 7) * 64 + (x >> 3);
  const int bh = gid >> 4, qt = gid & 15;
  const int b = bh >> 4, h = bh & 15;

  const int tid = threadIdx.x;
  const int lane = tid & 63;
  const int wid = tid >> 6;
  const int ql = lane & 31;
  const int hi = lane >> 5;

  __shared__ alignas(16) half_t Klds[64 * 64];   // [kv][d], xor-swizzled
  __shared__ alignas(16) half_t Vlds[64 * 64];   // [dv][kv], xor-swizzled
  __shared__ alignas(16) float  Olds[128 * 64];  // ctx transpose buffer

  const half_t* kbase = kbuf + (size_t)bh * (kLM * kDH);
  const half_t* vtbase = vtbuf + (size_t)bh * (kDH * kLM);
  const int* mbase = amask + b * kLM;

  // Q fragments (B-operand): lane = col q, holds d = ks*16 + hi*8 + j
  const int qg = qt * 128 + wid * 32 + ql;
  halfx8 qf[4];
#pragma unroll
  for (int ks = 0; ks < 4; ++ks)
    qf[ks] = *(const halfx8*)(qbuf + ((size_t)bh * kLD + qg) * kDH + ks * 16 + hi * 8);

  floatx16 ctx0 = {}, ctx1 = {};
  float m_run = -1e30f, l_run = 0.0f;

  for (int kv0 = 0; kv0 < kLM; kv0 += 64) {
    // reg-stage K tile [64 kv][64 d] and V^T tile [64 dv][64 kv]
    int4 stg[4];
#pragma unroll
    for (int i = 0; i < 2; ++i) {
      const int c = tid + 256 * i;
      const int row = c >> 3, c16 = c & 7;
      stg[i]     = *(const int4*)(kbase + (size_t)(kv0 + row) * kDH + c16 * 8);
      stg[2 + i] = *(const int4*)(vtbase + (size_t)row * kLM + kv0 + c16 * 8);
    }
    // attention-mask ints for the rows this lane will own
    int4 mi0[4], mi1[4];
#pragma unroll
    for (int g = 0; g < 4; ++g) {
      mi0[g] = *(const int4*)(mbase + kv0 + g * 8 + hi * 4);
      mi1[g] = *(const int4*)(mbase + kv0 + 32 + g * 8 + hi * 4);
    }

    __syncthreads();  // previous tile's LDS reads complete
#pragma unroll
    for (int i = 0; i < 2; ++i) {
      const int c = tid + 256 * i;
      const int row = c >> 3, c16 = c & 7;
      const int off = (row * 128 + c16 * 16) ^ ((row & 7) << 4);
      *(int4*)((char*)Klds + off) = stg[i];
      *(int4*)((char*)Vlds + off) = stg[2 + i];
    }
    __syncthreads();

    // S^T[kv][q] = K · Q^T  (swapped operands; 2 kv-subtiles x 4 d-slices)
    floatx16 S0 = {}, S1 = {};
#pragma unroll
    for (int ks = 0; ks < 4; ++ks) {
      const int off0 = (ql * 128 + ks * 32 + hi * 16) ^ ((ql & 7) << 4);
      halfx8 kf0 = *(const halfx8*)((const char*)Klds + off0);
      S0 = __builtin_amdgcn_mfma_f32_32x32x16_f16(kf0, qf[ks], S0, 0, 0, 0);
      const int off1 = ((32 + ql) * 128 + ks * 32 + hi * 16) ^ ((ql & 7) << 4);
      halfx8 kf1 = *(const halfx8*)((const char*)Klds + off1);
      S1 = __builtin_amdgcn_mfma_f32_32x32x16_f16(kf1, qf[ks], S1, 0, 0, 0);
    }

    // additive mask: row kv = (r&3) + 8*(r>>2) + 4*hi (+32 for S1)
#pragma unroll
    for (int g = 0; g < 4; ++g) {
#pragma unroll
      for (int j = 0; j < 4; ++j) {
        S0[g * 4 + j] += (((const int*)&mi0[g])[j] ? 0.0f : -1e30f);
        S1[g * 4 + j] += (((const int*)&mi1[g])[j] ? 0.0f : -1e30f);
      }
    }

    // online softmax, exp2 domain, fully in-register (one q per lane)
    float mx = S0[0];
#pragma unroll
    for (int i = 1; i < 16; ++i) mx = fmaxf(mx, S0[i]);
#pragma unroll
    for (int i = 0; i < 16; ++i) mx = fmaxf(mx, S1[i]);
    mx = fmaxf(mx, __shfl_xor(mx, 32));
    const float m_new = fmaxf(m_run, mx);
    const float scale = exp2_fast(m_run - m_new);
    m_run = m_new;

    float ps = 0.0f;
#pragma unroll
    for (int i = 0; i < 16; ++i) { S0[i] = exp2_fast(S0[i] - m_run); ps += S0[i]; }
#pragma unroll
    for (int i = 0; i < 16; ++i) { S1[i] = exp2_fast(S1[i] - m_run); ps += S1[i]; }
    ps += __shfl_xor(ps, 32);
    l_run = l_run * scale + ps;
#pragma unroll
    for (int i = 0; i < 16; ++i) { ctx0[i] *= scale; ctx1[i] *= scale; }

    // pack P^T into PV B-fragments: cvt_pkrtz pairs + permlane32_swap
    halfx8 pb[4];
#pragma unroll
    for (int sl = 0; sl < 4; ++sl) {
      const floatx16& P = (sl < 2) ? S0 : S1;
      const int rA = (sl & 1) * 8;
      unsigned wa = __builtin_bit_cast(unsigned, __builtin_amdgcn_cvt_pkrtz(P[rA + 0], P[rA + 1]));
      unsigned wb = __builtin_bit_cast(unsigned, __builtin_amdgcn_cvt_pkrtz(P[rA + 2], P[rA + 3]));
      unsigned wc = __builtin_bit_cast(unsigned, __builtin_amdgcn_cvt_pkrtz(P[rA + 4], P[rA + 5]));
      unsigned wd = __builtin_bit_cast(unsigned, __builtin_amdgcn_cvt_pkrtz(P[rA + 6], P[rA + 7]));
      uintx2 s1 = __builtin_amdgcn_permlane32_swap(wa, wc, false, false);
      uintx2 s2 = __builtin_amdgcn_permlane32_swap(wb, wd, false, false);
      uintx4 u;
      u[0] = s1[0]; u[1] = s2[0]; u[2] = s1[1]; u[3] = s2[1];
      pb[sl] = __builtin_bit_cast(halfx8, u);
    }

    // ctx^T += V^T · P^T  (2 dv-subtiles x 4 kv-slices)
#pragma unroll
    for (int sl = 0; sl < 4; ++sl) {
      const int off0 = (ql * 128 + sl * 32 + hi * 16) ^ ((ql & 7) << 4);
      halfx8 vf0 = *(const halfx8*)((const char*)Vlds + off0);
      ctx0 = __builtin_amdgcn_mfma_f32_32x32x16_f16(vf0, pb[sl], ctx0, 0, 0, 0);
      const int off1 = ((32 + ql) * 128 + sl * 32 + hi * 16) ^ ((ql & 7) << 4);
      halfx8 vf1 = *(const halfx8*)((const char*)Vlds + off1);
      ctx1 = __builtin_amdgcn_mfma_f32_32x32x16_f16(vf1, pb[sl], ctx1, 0, 0, 0);
    }
  }

  // epilogue: normalize + head-mask, transpose via LDS, coalesced f32 stores
  const int hmv = hmask[b * kLD + qg];
  const float inv = (hmv ? 0.0f : 1.0f) / l_run;
  const int qb = wid * 32 + ql;
#pragma unroll
  for (int g = 0; g < 4; ++g) {
#pragma unroll
    for (int pr = 0; pr < 2; ++pr) {
      const int r = g * 4 + pr * 2;
      const int dv0 = pr * 2 + 8 * g + 4 * hi;
      const int off0 = (qb * 256 + dv0 * 4) ^ ((qb & 7) << 4);
      *(float2*)((char*)Olds + off0) = make_float2(ctx0[r] * inv, ctx0[r + 1] * inv);
      const int off1 = (qb * 256 + (dv0 + 32) * 4) ^ ((qb & 7) << 4);
      *(float2*)((char*)Olds + off1) = make_float2(ctx1[r] * inv, ctx1[r + 1] * inv);
    }
  }
  __syncthreads();
#pragma unroll
  for (int p = 0; p < 8; ++p) {
    const int idx = p * 256 + tid;
    const int qb2 = idx >> 4, c4 = idx & 15;
    const int off = (qb2 * 256 + c4 * 16) ^ ((qb2 & 7) << 4);
    float4 v = *(const float4*)((const char*)Olds + off);
    *(float4*)(out + (((size_t)(b * kLD + qt * 128 + qb2)) << 10) + h * 64 + c4 * 4) = v;
  }
}

// ---------------------------------------------------------------------------
extern "C" void kernel_launch(void* const* d_in, const int* in_sizes, int n_in,
                              void* d_out, int out_size, void* d_ws, size_t ws_size,
                              hipStream_t stream)
{
  const float* hs   = (const float*)d_in[0];
  const float* ehs  = (const float*)d_in[1];
  const int*   am   = (const int*)d_in[2];
  const int*   hm   = (const int*)d_in[3];
  const float* Wq   = (const float*)d_in[4];
  const float* bq   = (const float*)d_in[5];
  const float* Wk   = (const float*)d_in[6];
  const float* bk   = (const float*)d_in[7];
  const float* Wv   = (const float*)d_in[8];
  const float* bv   = (const float*)d_in[9];
  float* out = (float*)d_out;

  char* ws = (char*)d_ws;
  half_t* xdec_h = (half_t*)(ws);
  half_t* xenc_h = (half_t*)(ws + (8ull << 20));
  half_t* wq_h   = (half_t*)(ws + (16ull << 20));
  half_t* wk_h   = (half_t*)(ws + (18ull << 20));
  half_t* wv_h   = (half_t*)(ws + (20ull << 20));
  half_t* q_buf  = (half_t*)(ws + (22ull << 20));
  half_t* k_buf  = (half_t*)(ws + (30ull << 20));
  half_t* vt_buf = (half_t*)(ws + (38ull << 20));

  convert_all<<<11264, 256, 0, stream>>>(hs, ehs, Wq, Wk, Wv,
                                         xdec_h, xenc_h, wq_h, wk_h, wv_h);
  qkv_gemm<<<dim3(32, 8, 3), 256, 0, stream>>>(xdec_h, xenc_h, wq_h, wk_h, wv_h,
                                               bq, bk, bv, q_buf, k_buf, vt_buf);
  attn_kernel<<<512, 256, 0, stream>>>(q_buf, k_buf, vt_buf, am, hm, out);
}